// Round 1
// baseline (37.271 us; speedup 1.0000x reference)
//
#include <hip/hip_runtime.h>
#include <hip/hip_bf16.h>

#define M_DIM 64
#define K_DIM 4096
#define N_DIM 11008

typedef __attribute__((ext_vector_type(4))) float f32x4;
typedef __attribute__((ext_vector_type(8))) short s16x8;
typedef __attribute__((ext_vector_type(4))) short s16x4;

__device__ __forceinline__ short f2bf(float f) {
    union { float f; unsigned int u; } un; un.f = f;
    unsigned int u = un.u;
    u += 0x7fffu + ((u >> 16) & 1u);   // round to nearest even
    return (short)(u >> 16);
}

// Tile: [M=64, N=64] per workgroup, K-chunk = 1024 (blockIdx.y of 4).
// 4 waves; wave w computes all 4 M-tiles of its 16-wide N column tile.
__global__ __launch_bounds__(256) void w4_gemm(
    const float* __restrict__ x,          // [64, 4096] f32
    const int*   __restrict__ qw,         // [2752, 4096] packed (low 16 bits)
    const float* __restrict__ scale,      // [11008]
    const float* __restrict__ zp,         // [11008]
    const float* __restrict__ bias,       // [11008]
    float*       __restrict__ out)        // [64, 11008] f32
{
    // Swizzled LDS tiles: row-major [row][64 bf16], 8 chunks of 16B per row,
    // chunk index XORed with (row&7) to avoid stride-128B bank conflicts.
    __shared__ s16x8 Xt[64 * 8];
    __shared__ s16x8 Wt[64 * 8];

    const int tid  = threadIdx.x;
    const int lane = tid & 63;
    const int wave = tid >> 6;
    const int n0   = blockIdx.x * 64;
    const int kc0  = blockIdx.y * 1024;

    // ---- W staging constants (each thread owns one n row, 4 words/k-step)
    const int qidx = tid >> 4;            // 0..15  (nq offset within block)
    const int u    = tid & 15;            // word group
    const int n_local = 4 * qidx + (u >> 2);
    const int t0   = 4 * (u & 3);         // t values t0..t0+3 (s = 4u+j, t=s&15)
    const int halfsel = (u & 3) >> 1;     // which 32-col half of the 64 group
    const float sc = scale[n0 + n_local];
    const float z  = zp[n0 + n_local];
    const long long wrow = (long long)(blockIdx.x * 16 + qidx) * K_DIM;

    // ---- X staging constants
    const int xrow = tid >> 2;            // 0..63
    const int xq   = tid & 3;             // quarter of the 64-k group

    f32x4 acc[4] = {};

    for (int step = 0; step < 16; ++step) {
        const int k0 = kc0 + step * 64;
        __syncthreads();   // previous iteration's reads done before overwrite

        // ---- stage X: x[0:64, k0:k0+64] f32 -> bf16, swizzled
        {
            const float* src = x + (size_t)xrow * K_DIM + k0 + xq * 16;
            f32x4 v0 = *(const f32x4*)(src + 0);
            f32x4 v1 = *(const f32x4*)(src + 4);
            f32x4 v2 = *(const f32x4*)(src + 8);
            f32x4 v3 = *(const f32x4*)(src + 12);
            s16x8 p0, p1;
#pragma unroll
            for (int e = 0; e < 4; ++e) {
                p0[e]     = f2bf(v0[e]);
                p0[4 + e] = f2bf(v1[e]);
                p1[e]     = f2bf(v2[e]);
                p1[4 + e] = f2bf(v3[e]);
            }
            const int c0 = xq * 2;
            Xt[xrow * 8 + ((c0)     ^ (xrow & 7))] = p0;
            Xt[xrow * 8 + ((c0 + 1) ^ (xrow & 7))] = p1;
        }

        // ---- stage W: 16 rows-of-block? no: 64 n rows x 64 k, dequant int4->bf16
        {
            const int4 w4 = *(const int4*)(qw + wrow + k0 + 4 * u);
            const int wv[4] = { w4.x, w4.y, w4.z, w4.w };
            short vals[4][4];
#pragma unroll
            for (int j = 0; j < 4; ++j) {
#pragma unroll
                for (int i = 0; i < 4; ++i) {
                    const int nib = (wv[j] >> (4 * i)) & 0xF;
                    vals[i][j] = f2bf(((float)nib - z) * sc);
                }
            }
            // nibble i of word t lands at col (t>=8?32:0) + (t&7) + 8i;
            // j=0..3 are k-consecutive -> one b64 write per i.
            char* rowbase = (char*)Wt + n_local * 128;
#pragma unroll
            for (int i = 0; i < 4; ++i) {
                const int c = (halfsel << 2) | i;
                s16x4 pk = { vals[i][0], vals[i][1], vals[i][2], vals[i][3] };
                *(s16x4*)(rowbase + (((c ^ (n_local & 7)) << 4)) + ((t0 & 7) << 1)) = pk;
            }
        }

        __syncthreads();

        // ---- MFMA: 2 k-halves x 4 M-tiles
        const int rb = wave * 16 + (lane & 15);
        const char* wbase = (const char*)Wt + rb * 128;
        const int cg = lane >> 4;
#pragma unroll
        for (int kk = 0; kk < 2; ++kk) {
            const int cB = kk * 4 + cg;
            s16x8 bfrag = *(const s16x8*)(wbase + ((cB ^ (rb & 7)) << 4));
#pragma unroll
            for (int mt = 0; mt < 4; ++mt) {
                const int ra = mt * 16 + (lane & 15);
                s16x8 afrag = *(const s16x8*)((const char*)Xt + ra * 128 +
                                              (((kk * 4 + cg) ^ (ra & 7)) << 4));
                acc[mt] = __builtin_amdgcn_mfma_f32_16x16x32_bf16(afrag, bfrag, acc[mt], 0, 0, 0);
            }
        }
    }

    // ---- epilogue: atomic accumulate K-partials; chunk 0 adds bias
    const int nn = n0 + wave * 16 + (lane & 15);
    const float bv = (blockIdx.y == 0) ? bias[nn] : 0.0f;
#pragma unroll
    for (int mt = 0; mt < 4; ++mt) {
#pragma unroll
        for (int r = 0; r < 4; ++r) {
            const int m = mt * 16 + (lane >> 4) * 4 + r;
            atomicAdd(out + (size_t)m * N_DIM + nn, acc[mt][r] + bv);
        }
    }
}

extern "C" void kernel_launch(void* const* d_in, const int* in_sizes, int n_in,
                              void* d_out, int out_size, void* d_ws, size_t ws_size,
                              hipStream_t stream) {
    const float* x     = (const float*)d_in[0];
    const int*   qw    = (const int*)d_in[1];
    const float* scale = (const float*)d_in[2];
    const float* zp    = (const float*)d_in[3];
    const float* bias  = (const float*)d_in[4];
    float* out = (float*)d_out;

    hipMemsetAsync(d_out, 0, (size_t)out_size * sizeof(float), stream);
    dim3 grid(N_DIM / 64, 4);
    w4_gemm<<<grid, 256, 0, stream>>>(x, qw, scale, zp, bias, out);
}

// Round 2
// 33.502 us; speedup vs baseline: 1.1125x; 1.1125x over previous
//
#include <hip/hip_runtime.h>
#include <hip/hip_bf16.h>

#define K_DIM 4096
#define N_DIM 11008

typedef __attribute__((ext_vector_type(4))) float f32x4;
typedef _Float16 half8 __attribute__((ext_vector_type(8)));
typedef _Float16 half2v __attribute__((ext_vector_type(2)));
typedef unsigned int uint32;

// ---------------- prep: x[64,4096] f32 -> xp f16, fragment-major, AWQ-permuted
// xp slot (kg, h, mt): 1 KB block at byte offset (((kg*2+h)*4+mt)*64 + lane)*16.
// Lane element e: m = mt*16+(lane&15); k' = h*32+(lane>>4)*8+e;
//   t = k'>>2, i' = k'&3, i = ((i'&1)<<1)|(i'>>1)   (within-word order nib0,nib2,nib1,nib3)
//   col = (t>=8?32:0) + (t&7) + 8i;  k = kg*64 + col   (validated mapping, round 1)
__global__ __launch_bounds__(256) void prep_x(const float* __restrict__ x,
                                              unsigned short* __restrict__ xp) {
    const int g = blockIdx.x * 256 + threadIdx.x;      // 0..32767
    const int lane = g & 63, mt = (g >> 6) & 3, h = (g >> 8) & 1, kg = g >> 9;
    const int m = mt * 16 + (lane & 15), qq = lane >> 4;
    union { unsigned short v[8]; uint4 u4; } r;
#pragma unroll
    for (int e = 0; e < 8; ++e) {
        const int kp = h * 32 + qq * 8 + e;
        const int t = kp >> 2, ip = kp & 3;
        const int i = ((ip & 1) << 1) | (ip >> 1);
        const int col = ((t >> 3) << 5) + (t & 7) + (i << 3);
        const _Float16 hf = (_Float16)x[m * K_DIM + kg * 64 + col];
        r.v[e] = __builtin_bit_cast(unsigned short, hf);
    }
    *(uint4*)(xp + (size_t)g * 8) = r.u4;
}

// ---------------- dequant 2 packed words -> one B-fragment (8 f16, k'-ordered)
__device__ __forceinline__ half8 build_bfrag(int w0, int w1, half2v s2, half2v c2) {
    union { half8 h; half2v p[4]; } r;
    const half2v k1024 = {(_Float16)1024.0f, (_Float16)1024.0f};
    const uint32 u0 = (uint32)(w0 & 0xF)        | (((uint32)w0 & 0xF00u) << 8) | 0x64006400u;
    const uint32 u1 = (uint32)((w0 >> 4) & 0xF) | (((uint32)w0 & 0xF000u) << 4) | 0x64006400u;
    const uint32 u2 = (uint32)(w1 & 0xF)        | (((uint32)w1 & 0xF00u) << 8) | 0x64006400u;
    const uint32 u3 = (uint32)((w1 >> 4) & 0xF) | (((uint32)w1 & 0xF000u) << 4) | 0x64006400u;
    half2v q;
    q = __builtin_bit_cast(half2v, u0) - k1024; r.p[0] = q * s2 + c2;
    q = __builtin_bit_cast(half2v, u1) - k1024; r.p[1] = q * s2 + c2;
    q = __builtin_bit_cast(half2v, u2) - k1024; r.p[2] = q * s2 + c2;
    q = __builtin_bit_cast(half2v, u3) - k1024; r.p[3] = q * s2 + c2;
    return r.h;
}

// ---------------- main GEMM: 688 WGs x 256 thr; wave j = K-quarter j,
// all 4 waves share one 16-col tile; LDS reduce; plain stores (no memset/atomics)
__global__ __launch_bounds__(256) void w4_gemm(
    const unsigned short* __restrict__ xp,   // [512 KB] f16, fragment-major
    const int*   __restrict__ qw,            // [2752, 4096] packed
    const float* __restrict__ scale,
    const float* __restrict__ zp,
    const float* __restrict__ bias,
    float*       __restrict__ out)           // [64, 11008] f32
{
    __shared__ f32x4 part[1024];             // [j][mt][q][nl] -> 16 KB

    const int tid = threadIdx.x, lane = tid & 63, j = tid >> 6;
    const int nl = lane & 15, q = lane >> 4;
    const int n0 = blockIdx.x * 16, nn = n0 + nl;

    const float s = scale[nn], z = zp[nn];
    const _Float16 sh = (_Float16)s;
    const _Float16 ch = (_Float16)(-z * s);
    const half2v s2 = {sh, sh}, c2 = {ch, ch};

    // packed word base for this lane's output row nn:  qw[nn>>2][_ + (nn&3)*16 + t]
    const int* qb = qw + ((size_t)(nn >> 2) * K_DIM) + ((nn & 3) * 16) + 2 * q;

    f32x4 acc[4] = {{0,0,0,0},{0,0,0,0},{0,0,0,0},{0,0,0,0}};

    const int kg_end = j * 16 + 16;
    for (int kg = j * 16; kg < kg_end; ++kg) {
        const int2 wA = *(const int2*)(qb + kg * 64);      // t = 2q, 2q+1     (h=0)
        const int2 wB = *(const int2*)(qb + kg * 64 + 8);  // t = 2q+8, 2q+9   (h=1)
        const unsigned short* ab = xp + (size_t)kg * 4096; // 8 KB block, in halves

        half8 bf = build_bfrag(wA.x, wA.y, s2, c2);
#pragma unroll
        for (int mt = 0; mt < 4; ++mt) {
            const half8 af = *(const half8*)(ab + mt * 512 + lane * 8);
            acc[mt] = __builtin_amdgcn_mfma_f32_16x16x32_f16(af, bf, acc[mt], 0, 0, 0);
        }
        bf = build_bfrag(wB.x, wB.y, s2, c2);
#pragma unroll
        for (int mt = 0; mt < 4; ++mt) {
            const half8 af = *(const half8*)(ab + (4 + mt) * 512 + lane * 8);
            acc[mt] = __builtin_amdgcn_mfma_f32_16x16x32_f16(af, bf, acc[mt], 0, 0, 0);
        }
    }

    // partials: part[(j*16 + mt*4 + q)*16 + nl]
#pragma unroll
    for (int mt = 0; mt < 4; ++mt)
        part[(j * 16 + mt * 4 + q) * 16 + nl] = acc[mt];
    __syncthreads();

    // reduce + bias + store: thread t owns (mt, q, nl) = bits of t; rows m = mt*16+q*4+r
    {
        const int rmt = tid >> 6, rq = (tid >> 4) & 3, rnl = tid & 15;
        const int base = rmt * 64 + rq * 16 + rnl;
        f32x4 sum = part[base];
        sum += part[256 + base];
        sum += part[512 + base];
        sum += part[768 + base];
        const float bv = bias[n0 + rnl];
        const int m0 = rmt * 16 + rq * 4;
#pragma unroll
        for (int r = 0; r < 4; ++r)
            out[(size_t)(m0 + r) * N_DIM + n0 + rnl] = sum[r] + bv;
    }
}

extern "C" void kernel_launch(void* const* d_in, const int* in_sizes, int n_in,
                              void* d_out, int out_size, void* d_ws, size_t ws_size,
                              hipStream_t stream) {
    const float* x     = (const float*)d_in[0];
    const int*   qw    = (const int*)d_in[1];
    const float* scale = (const float*)d_in[2];
    const float* zp    = (const float*)d_in[3];
    const float* bias  = (const float*)d_in[4];
    float* out = (float*)d_out;
    unsigned short* xp = (unsigned short*)d_ws;   // 512 KB scratch

    prep_x<<<128, 256, 0, stream>>>(x, xp);
    w4_gemm<<<N_DIM / 16, 256, 0, stream>>>(xp, qw, scale, zp, bias, out);
}

// Round 3
// 30.051 us; speedup vs baseline: 1.2403x; 1.1149x over previous
//
#include <hip/hip_runtime.h>
#include <hip/hip_bf16.h>

#define K_DIM 4096
#define N_DIM 11008

typedef __attribute__((ext_vector_type(4))) float f32x4;
typedef _Float16 half8 __attribute__((ext_vector_type(8)));
typedef _Float16 half2v __attribute__((ext_vector_type(2)));
typedef unsigned int uint32;

// ---------------- prep: x[64,4096] f32 -> xp f16, fragment-major, AWQ-permuted
// xp slot (kg, h, mt): halfword offset ((kg*2+h)*4+mt)*512 + lane*8.
// Lane element e: m = mt*16+(lane&15); k' = h*32+(lane>>4)*8+e;
//   t = k'>>2, i' = k'&3, i = ((i'&1)<<1)|(i'>>1); col = (t>=8?32:0)+(t&7)+8i
// (mapping validated by round-1/2 passing correctness)
__global__ __launch_bounds__(256) void prep_x(const float* __restrict__ x,
                                              unsigned short* __restrict__ xp) {
    const int g = blockIdx.x * 256 + threadIdx.x;      // 0..32767
    const int lane = g & 63, mt = (g >> 6) & 3, h = (g >> 8) & 1, kg = g >> 9;
    const int m = mt * 16 + (lane & 15), qq = lane >> 4;
    union { unsigned short v[8]; uint4 u4; } r;
#pragma unroll
    for (int e = 0; e < 8; ++e) {
        const int kp = h * 32 + qq * 8 + e;
        const int t = kp >> 2, ip = kp & 3;
        const int i = ((ip & 1) << 1) | (ip >> 1);
        const int col = ((t >> 3) << 5) + (t & 7) + (i << 3);
        const _Float16 hf = (_Float16)x[m * K_DIM + kg * 64 + col];
        r.v[e] = __builtin_bit_cast(unsigned short, hf);
    }
    *(uint4*)(xp + (size_t)g * 8) = r.u4;
}

// ---------------- dequant 2 packed words -> one B-fragment (8 f16, k'-ordered)
__device__ __forceinline__ half8 build_bfrag(int w0, int w1, half2v s2, half2v c2) {
    union { half8 h; half2v p[4]; } r;
    const half2v k1024 = {(_Float16)1024.0f, (_Float16)1024.0f};
    const uint32 u0 = (uint32)(w0 & 0xF)        | (((uint32)w0 & 0xF00u) << 8) | 0x64006400u;
    const uint32 u1 = (uint32)((w0 >> 4) & 0xF) | (((uint32)w0 & 0xF000u) << 4) | 0x64006400u;
    const uint32 u2 = (uint32)(w1 & 0xF)        | (((uint32)w1 & 0xF00u) << 8) | 0x64006400u;
    const uint32 u3 = (uint32)((w1 >> 4) & 0xF) | (((uint32)w1 & 0xF000u) << 4) | 0x64006400u;
    half2v q;
    q = __builtin_bit_cast(half2v, u0) - k1024; r.p[0] = q * s2 + c2;
    q = __builtin_bit_cast(half2v, u1) - k1024; r.p[1] = q * s2 + c2;
    q = __builtin_bit_cast(half2v, u2) - k1024; r.p[2] = q * s2 + c2;
    q = __builtin_bit_cast(half2v, u3) - k1024; r.p[3] = q * s2 + c2;
    return r.h;
}

// ---------------- main GEMM: grid (344, 4), 256 thr (4 waves).
// Wave (nx, ky, j): output tile 64m x 32n (n0 = nx*32), K-slice kg in
// [ky*16 + j*4, +4). A-fragments shared by both 16-col B tiles.
// In-WG LDS reduce over j -> one 64x32 f32 partial per (nx,ky) into ws.
__global__ __launch_bounds__(256) void w4_gemm(
    const unsigned short* __restrict__ xp,   // f16, fragment-major
    const int*   __restrict__ qw,            // [2752, 4096] packed
    const float* __restrict__ scale,
    const float* __restrict__ zp,
    f32x4*       __restrict__ ws)            // partials [344*4][512] f32x4
{
    __shared__ f32x4 part[2048];             // [j][nt][mt][q][nl] -> 32 KB

    const int tid = threadIdx.x, lane = tid & 63, j = tid >> 6;
    const int nl = lane & 15, q = lane >> 4;
    const int nx = blockIdx.x, ky = blockIdx.y;
    const int n0 = nx * 32;
    const int nnA = n0 + nl, nnB = n0 + 16 + nl;

    const float sA = scale[nnA], zA = zp[nnA];
    const float sB = scale[nnB], zB = zp[nnB];
    const _Float16 shA = (_Float16)sA, chA = (_Float16)(-zA * sA);
    const _Float16 shB = (_Float16)sB, chB = (_Float16)(-zB * sB);
    const half2v s2A = {shA, shA}, c2A = {chA, chA};
    const half2v s2B = {shB, shB}, c2B = {chB, chB};

    const int* qbA = qw + ((size_t)(nnA >> 2) * K_DIM) + ((nnA & 3) * 16) + 2 * q;
    const int* qbB = qw + ((size_t)(nnB >> 2) * K_DIM) + ((nnB & 3) * 16) + 2 * q;

    f32x4 acc[2][4] = {};

    const int kg0 = ky * 16 + j * 4;
#pragma unroll
    for (int it = 0; it < 4; ++it) {
        const int kg = kg0 + it;
        const int2 a0 = *(const int2*)(qbA + kg * 64);       // t=2q,2q+1   (h=0)
        const int2 a1 = *(const int2*)(qbA + kg * 64 + 8);   // t=2q+8,2q+9 (h=1)
        const int2 b0 = *(const int2*)(qbB + kg * 64);
        const int2 b1 = *(const int2*)(qbB + kg * 64 + 8);
        const unsigned short* ab = xp + (size_t)kg * 4096;

        const half8 bfA0 = build_bfrag(a0.x, a0.y, s2A, c2A);
        const half8 bfB0 = build_bfrag(b0.x, b0.y, s2B, c2B);
#pragma unroll
        for (int mt = 0; mt < 4; ++mt) {
            const half8 af = *(const half8*)(ab + mt * 512 + lane * 8);
            acc[0][mt] = __builtin_amdgcn_mfma_f32_16x16x32_f16(af, bfA0, acc[0][mt], 0, 0, 0);
            acc[1][mt] = __builtin_amdgcn_mfma_f32_16x16x32_f16(af, bfB0, acc[1][mt], 0, 0, 0);
        }
        const half8 bfA1 = build_bfrag(a1.x, a1.y, s2A, c2A);
        const half8 bfB1 = build_bfrag(b1.x, b1.y, s2B, c2B);
#pragma unroll
        for (int mt = 0; mt < 4; ++mt) {
            const half8 af = *(const half8*)(ab + (4 + mt) * 512 + lane * 8);
            acc[0][mt] = __builtin_amdgcn_mfma_f32_16x16x32_f16(af, bfA1, acc[0][mt], 0, 0, 0);
            acc[1][mt] = __builtin_amdgcn_mfma_f32_16x16x32_f16(af, bfB1, acc[1][mt], 0, 0, 0);
        }
    }

    // partials: part[((j*2+nt)*4+mt)*64 + q*16 + nl]
#pragma unroll
    for (int nt = 0; nt < 2; ++nt)
#pragma unroll
        for (int mt = 0; mt < 4; ++mt)
            part[((j * 2 + nt) * 4 + mt) * 64 + q * 16 + nl] = acc[nt][mt];
    __syncthreads();

    // reduce over j, write ws[(nx*4+ky)*512 + s], s = (nt,mt,q,nl)
    f32x4* wsb = ws + ((size_t)nx * 4 + ky) * 512;
#pragma unroll
    for (int ss = 0; ss < 2; ++ss) {
        const int s = tid + ss * 256;
        f32x4 v = part[s];
        v += part[512 + s];
        v += part[1024 + s];
        v += part[1536 + s];
        wsb[s] = v;
    }
}

// ---------------- final reduce: sum 4 ky partials + bias -> out
__global__ __launch_bounds__(256) void reduce_k(
    const f32x4* __restrict__ ws,
    const float* __restrict__ bias,
    float*       __restrict__ out)
{
    const int nx = blockIdx.x, tid = threadIdx.x;
    const f32x4* wsb = ws + (size_t)nx * 4 * 512;
#pragma unroll
    for (int ss = 0; ss < 2; ++ss) {
        const int s = tid + ss * 256;
        f32x4 v = wsb[s];
        v += wsb[512 + s];
        v += wsb[1024 + s];
        v += wsb[1536 + s];
        const int nt = s >> 8, mt = (s >> 6) & 3, qq = (s >> 4) & 3, nl = s & 15;
        const int n = nx * 32 + nt * 16 + nl;
        const float bv = bias[n];
        const int m0 = mt * 16 + qq * 4;
#pragma unroll
        for (int r = 0; r < 4; ++r)
            out[(size_t)(m0 + r) * N_DIM + n] = v[r] + bv;
    }
}

extern "C" void kernel_launch(void* const* d_in, const int* in_sizes, int n_in,
                              void* d_out, int out_size, void* d_ws, size_t ws_size,
                              hipStream_t stream) {
    const float* x     = (const float*)d_in[0];
    const int*   qw    = (const int*)d_in[1];
    const float* scale = (const float*)d_in[2];
    const float* zp    = (const float*)d_in[3];
    const float* bias  = (const float*)d_in[4];
    float* out = (float*)d_out;

    unsigned short* xp = (unsigned short*)d_ws;                  // 512 KB
    f32x4* part_ws = (f32x4*)((char*)d_ws + (1 << 20));          // 11.3 MB partials

    prep_x<<<128, 256, 0, stream>>>(x, xp);
    dim3 grid(344, 4);
    w4_gemm<<<grid, 256, 0, stream>>>(xp, qw, scale, zp, part_ws);
    reduce_k<<<344, 256, 0, stream>>>(part_ws, bias, out);
}